// Round 18
// baseline (2429.635 us; speedup 1.0000x reference)
//
#include <hip/hip_runtime.h>
#include <cstddef>

#define T_STEPS 1024
#define NB      64
#define DIN     128
#define HID     256
#define WPG     16

typedef unsigned short u16;
typedef unsigned int   u32;
typedef unsigned long long u64;
typedef __attribute__((ext_vector_type(8))) short short8;
typedef __attribute__((ext_vector_type(4))) float f32x4;

// ws byte offsets
#define WG_OFF   0u          // bf16 weights [2][1024 rows j*4+q][384 k] = 1,572,864 B
#define BIAS_OFF 1572864u    // f32 [2][1024]
#define XB_OFF   1581056u    // bf16 x [1024][64][128] = 16,777,216 B
#define HB_OFF   18358272u   // u16 hbuf [2 par][8 grp][16 b][256 j] = 131,072 B
#define FL_OFF   18489344u   // u32 flags [8 grp][16 wg] = 512 B

#define OUT_MAIN (T_STEPS * NB * 2 * HID)
#define TAIL_H   OUT_MAIN
#define TAIL_C   (OUT_MAIN + 2 * NB * HID)

__device__ __forceinline__ u16 f2bf(float f) {
  unsigned u = __float_as_uint(f);
  return (u16)((u + 0x7fffu + ((u >> 16) & 1u)) >> 16);  // RNE
}
__device__ __forceinline__ float sigm(float v) { return 1.f / (1.f + __expf(-v)); }
__device__ __forceinline__ float tanh_fast(float x) {
  float e = __expf(-2.f * fabsf(x));
  float r = (1.f - e) / (1.f + e);
  return x < 0.f ? -r : r;
}

__global__ void prep_kernel(const float* __restrict__ x,
                            const float* __restrict__ Wih_f, const float* __restrict__ Whh_f,
                            const float* __restrict__ bih_f, const float* __restrict__ bhh_f,
                            const float* __restrict__ Wih_r, const float* __restrict__ Whh_r,
                            const float* __restrict__ bih_r, const float* __restrict__ bhh_r,
                            const float* __restrict__ hx,
                            u16* __restrict__ Wg, float* __restrict__ bias4,
                            u16* __restrict__ xb, u16* __restrict__ hbuf,
                            u32* __restrict__ flags) {
  // segments: W 786432 | bias 2048 | xb 8388608 | hx-cells 32768 | flags 128
  const int total = 786432 + 2048 + 8388608 + 32768 + 128;
  for (int i = blockIdx.x * blockDim.x + threadIdx.x; i < total;
       i += gridDim.x * blockDim.x) {
    if (i < 786432) {
      int d = i / 393216;
      int r = i - d * 393216;
      int rowg = r / 384, k = r - rowg * 384;   // rowg = j*4+q interleaved
      int j = rowg >> 2, q = rowg & 3;
      int g = q * HID + j;                      // torch gate row
      const float* Wih = d ? Wih_r : Wih_f;
      const float* Whh = d ? Whh_r : Whh_f;
      float v = (k < DIN) ? Wih[g * DIN + k] : Whh[g * HID + (k - DIN)];
      Wg[i] = f2bf(v);
    } else if (i < 786432 + 2048) {
      int r = i - 786432;
      int d = r >> 10, rowg = r & 1023;
      int j = rowg >> 2, q = rowg & 3;
      int g = q * HID + j;
      bias4[r] = d ? (bih_r[g] + bhh_r[g]) : (bih_f[g] + bhh_f[g]);
    } else if (i < 786432 + 2048 + 8388608) {
      int r = i - (786432 + 2048);
      xb[r] = f2bf(x[r]);                       // [t][b][k]
    } else if (i < 786432 + 2048 + 8388608 + 32768) {
      int r = i - (786432 + 2048 + 8388608);    // (d*64+b)*256 + j
      int d = r >> 14, b = (r >> 8) & 63, j = r & 255;
      int grp = d * 4 + (b >> 4), bb = b & 15;
      hbuf[((size_t)(8 + grp) * 16 + bb) * 256 + j] = f2bf(hx[r]);  // parity 1
      hbuf[((size_t)(0 + grp) * 16 + bb) * 256 + j] = 0;            // parity 0
    } else {
      flags[i - (786432 + 2048 + 8388608 + 32768)] = 0u;
    }
  }
}

#define MFMA __builtin_amdgcn_mfma_f32_16x16x32_bf16
#define ALD64(P) __hip_atomic_load((P), __ATOMIC_RELAXED, __HIP_MEMORY_SCOPE_AGENT)
#define ALD32(P) __hip_atomic_load((P), __ATOMIC_RELAXED, __HIP_MEMORY_SCOPE_AGENT)

// 128 WGs x 256 thr. grp = bid&7 (co-XCD under round-robin), jsl = bid>>3.
// grp = d*4 + btile: 8 groups x 16 WGs. Per WG: 64 gate rows, 16 batches.
// vs r17 (2049us): (1) per-producer value flags -- producer plain-stores
// flag[jsl]=s+1 (no RMW queue); (2) wave-cooperative self-release poll --
// each thread polls ITS producer's flag word (lane layout makes a wave's
// poll one coalesced 64B line read), B4 deleted, no double discovery;
// (3) two-accumulator MFMA chains (dep depth 12 -> 6).
__global__ __launch_bounds__(256, 1) void lstm_r18(
    const u16* __restrict__ Wg, const float* __restrict__ bias4,
    const u16* __restrict__ xb, const float* __restrict__ cx,
    u16* __restrict__ hbuf, u32* __restrict__ flags,
    float* __restrict__ out) {
  extern __shared__ char smem[];
  u16* xsh  = (u16*)smem;                 // [2][16][136]  8,704 B
  u16* hsh  = (u16*)(smem + 8704);        // [16][264]     8,448 B
  float* gl = (float*)(smem + 17152);     // [16][68]      4,352 B  (tot 21,504)

  const int tid = threadIdx.x;
  const int bid = blockIdx.x;
  const int grp = bid & 7;
  const int jsl = bid >> 3;
  const int d = grp >> 2, b0 = (grp & 3) * 16;
  const int w = tid >> 6, l = tid & 63;

  // one-time: 12 weight fragments -> named VGPRs (r13/r17-proven, no spill)
  const u16* wgb = Wg + ((size_t)(d * 1024 + jsl * 64 + w * 16 + (l & 15))) * 384
                      + (l >> 4) * 8;
  short8 Wx0 = *(const short8*)(wgb + 0);
  short8 Wx1 = *(const short8*)(wgb + 32);
  short8 Wx2 = *(const short8*)(wgb + 64);
  short8 Wx3 = *(const short8*)(wgb + 96);
  short8 Wh0 = *(const short8*)(wgb + 128);
  short8 Wh1 = *(const short8*)(wgb + 160);
  short8 Wh2 = *(const short8*)(wgb + 192);
  short8 Wh3 = *(const short8*)(wgb + 224);
  short8 Wh4 = *(const short8*)(wgb + 256);
  short8 Wh5 = *(const short8*)(wgb + 288);
  short8 Wh6 = *(const short8*)(wgb + 320);
  short8 Wh7 = *(const short8*)(wgb + 352);
  const float bv = bias4[d * 1024 + jsl * 64 + w * 16 + (l & 15)];

  // elementwise identity: 1 cell/thread: eb = batch, ej = local j
  const int eb = tid >> 4, ej = tid & 15;
  const int jglob = jsl * 16 + ej;
  float c_reg = cx[((size_t)d * NB + b0 + eb) * HID + jglob];

  const int xr_row = tid >> 4;            // x stage row (16 batches)
  const int xc = (tid & 15) * 8;          // 8 u16 = 16 B per thread
  const int pb = tid >> 4;                // h consumer batch
  const int cj0 = (tid & 15) * 16;        // 16 h cells per thread (producer = tid&15)
  const u32* myflag = flags + grp * WPG + (tid & 15);

  // prologue: stage x(t0), prefetch x(t1), issue h(init) loads (parity 1)
  { int t0 = d ? 1023 : 0;
    *(uint4*)&xsh[(0 * 16 + xr_row) * 136 + xc] =
        *(const uint4*)&xb[((size_t)t0 * NB + b0 + xr_row) * DIN + xc]; }
  uint4 xv;
  { int t1 = d ? 1022 : 1;
    xv = *(const uint4*)&xb[((size_t)t1 * NB + b0 + xr_row) * DIN + xc]; }
  u64 h0, h1, h2, h3;
  { const u64* hp = (const u64*)(hbuf + ((size_t)(8 + grp) * 16 + pb) * 256 + cj0);
    h0 = ALD64(hp + 0); h1 = ALD64(hp + 1); h2 = ALD64(hp + 2); h3 = ALD64(hp + 3); }
  __syncthreads();

  for (int s = 0; s < T_STEPS; ++s) {
    const int p = s & 1;
    const int t = d ? (1023 - s) : s;

    // park x(s+1) into the other buffer
    if (s < 1023) *(uint4*)&xsh[((p ^ 1) * 16 + xr_row) * 136 + xc] = xv;

    // x-part MFMA (hides in-flight h loads); weights from VGPRs, 2 chains
    f32x4 acc0 = {bv, bv, bv, bv}, acc1 = {0.f, 0.f, 0.f, 0.f};
    {
      const u16* xr = &xsh[(p * 16 + (l & 15)) * 136 + (l >> 4) * 8];
      acc0 = MFMA(*(const short8*)(xr + 0),  Wx0, acc0, 0, 0, 0);
      acc1 = MFMA(*(const short8*)(xr + 32), Wx1, acc1, 0, 0, 0);
      acc0 = MFMA(*(const short8*)(xr + 64), Wx2, acc0, 0, 0, 0);
      acc1 = MFMA(*(const short8*)(xr + 96), Wx3, acc1, 0, 0, 0);
    }
    // park h (waits vmcnt on h regs only)
    {
      uint4 H0, H1;
      H0.x = (u32)h0; H0.y = (u32)(h0 >> 32); H0.z = (u32)h1; H0.w = (u32)(h1 >> 32);
      H1.x = (u32)h2; H1.y = (u32)(h2 >> 32); H1.z = (u32)h3; H1.w = (u32)(h3 >> 32);
      *(uint4*)&hsh[pb * 264 + cj0] = H0;
      *(uint4*)&hsh[pb * 264 + cj0 + 8] = H1;
    }
    asm volatile("s_waitcnt lgkmcnt(0)" ::: "memory");
    __builtin_amdgcn_s_barrier();                // B1: h parked (joins self-release)

    // h-part MFMA: weights from registers, h fragments from LDS, 2 chains
    {
      const u16* hr = &hsh[(l & 15) * 264 + (l >> 4) * 8];
      acc0 = MFMA(*(const short8*)(hr + 0),   Wh0, acc0, 0, 0, 0);
      acc1 = MFMA(*(const short8*)(hr + 32),  Wh1, acc1, 0, 0, 0);
      acc0 = MFMA(*(const short8*)(hr + 64),  Wh2, acc0, 0, 0, 0);
      acc1 = MFMA(*(const short8*)(hr + 96),  Wh3, acc1, 0, 0, 0);
      acc0 = MFMA(*(const short8*)(hr + 128), Wh4, acc0, 0, 0, 0);
      acc1 = MFMA(*(const short8*)(hr + 160), Wh5, acc1, 0, 0, 0);
      acc0 = MFMA(*(const short8*)(hr + 192), Wh6, acc0, 0, 0, 0);
      acc1 = MFMA(*(const short8*)(hr + 224), Wh7, acc1, 0, 0, 0);
    }
    acc0 = acc0 + acc1;
    {
      int n = w * 16 + (l & 15);
      int m0 = (l >> 4) * 4;
      gl[(m0 + 0) * 68 + n] = acc0[0]; gl[(m0 + 1) * 68 + n] = acc0[1];
      gl[(m0 + 2) * 68 + n] = acc0[2]; gl[(m0 + 3) * 68 + n] = acc0[3];
    }
    asm volatile("s_waitcnt lgkmcnt(0)" ::: "memory");
    __builtin_amdgcn_s_barrier();                // B2: gates published

    // elementwise (all 256 threads) + agent h-store
    f32x4 g4 = *(const f32x4*)&gl[eb * 68 + 4 * ej];
    float ii = sigm(g4[0]), ff = sigm(g4[1]);
    float gg = tanh_fast(g4[2]), oo = sigm(g4[3]);
    float c = ff * c_reg + ii * gg;
    c_reg = c;
    float h = oo * tanh_fast(c);
    u16 hb16 = f2bf(h);
    __hip_atomic_store(hbuf + ((size_t)(p * 8 + grp) * 16 + eb) * 256 + jglob,
                       hb16, __ATOMIC_RELAXED, __HIP_MEMORY_SCOPE_AGENT);
    asm volatile("s_waitcnt vmcnt(0)" ::: "memory");   // h at LLC
    __builtin_amdgcn_s_barrier();                // B3: all h stores drained
    // per-producer value flag (plain store, no RMW)
    if (tid == 0 && s < 1023)
      __hip_atomic_store(flags + grp * WPG + jsl, (u32)(s + 1),
                         __ATOMIC_RELAXED, __HIP_MEMORY_SCOPE_AGENT);
    // fire-and-forget stores after the flag
    out[((size_t)t * NB + b0 + eb) * (2 * HID) + d * HID + jglob] = h;
    if (s == 1023) {
      out[TAIL_H + ((size_t)d * NB + b0 + eb) * HID + jglob] = h;
      out[TAIL_C + ((size_t)d * NB + b0 + eb) * HID + jglob] = c;
    }
    // x prefetch for s+2
    if (s < 1022) {
      int tn = d ? (1021 - s) : (s + 2);
      xv = *(const uint4*)&xb[((size_t)tn * NB + b0 + xr_row) * DIN + xc];
    }
    if (s < 1023) {
      // wave-cooperative self-release: each thread polls ITS producer's flag
      // (lanes of a wave cover the 16 words of one 64B line -> coalesced)
      const u32 want = (u32)(s + 1);
      while (ALD32(myflag) < want) { }
      // issue h(s) loads (parity p) -- hidden under next step's x-GEMM
      const u64* hp = (const u64*)(hbuf + ((size_t)(p * 8 + grp) * 16 + pb) * 256 + cj0);
      h0 = ALD64(hp + 0); h1 = ALD64(hp + 1); h2 = ALD64(hp + 2); h3 = ALD64(hp + 3);
    }
  }
}

extern "C" void kernel_launch(void* const* d_in, const int* in_sizes, int n_in,
                              void* d_out, int out_size, void* d_ws, size_t ws_size,
                              hipStream_t stream) {
  const float* x     = (const float*)d_in[0];
  const float* hx    = (const float*)d_in[1];
  const float* cx    = (const float*)d_in[2];
  const float* Wih_f = (const float*)d_in[3];
  const float* Whh_f = (const float*)d_in[4];
  const float* bih_f = (const float*)d_in[5];
  const float* bhh_f = (const float*)d_in[6];
  const float* Wih_r = (const float*)d_in[7];
  const float* Whh_r = (const float*)d_in[8];
  const float* bih_r = (const float*)d_in[9];
  const float* bhh_r = (const float*)d_in[10];
  float* out = (float*)d_out;

  u16* Wg      = (u16*)((char*)d_ws + WG_OFF);
  float* bias4 = (float*)((char*)d_ws + BIAS_OFF);
  u16* xb      = (u16*)((char*)d_ws + XB_OFF);
  u16* hbuf    = (u16*)((char*)d_ws + HB_OFF);
  u32* flags   = (u32*)((char*)d_ws + FL_OFF);

  // Request 86,016 B dynamic LDS (uses ~21.5 KB): forces 1 WG/CU.
  hipFuncSetAttribute((const void*)lstm_r18,
                      hipFuncAttributeMaxDynamicSharedMemorySize, 86016);

  hipLaunchKernelGGL(prep_kernel, dim3(2048), dim3(256), 0, stream,
                     x, Wih_f, Whh_f, bih_f, bhh_f, Wih_r, Whh_r, bih_r, bhh_r,
                     hx, Wg, bias4, xb, hbuf, flags);
  hipLaunchKernelGGL(lstm_r18, dim3(128), dim3(256), 86016, stream,
                     Wg, bias4, xb, cx, hbuf, flags, out);
}

// Round 19
// 2087.760 us; speedup vs baseline: 1.1638x; 1.1638x over previous
//
#include <hip/hip_runtime.h>
#include <cstddef>

#define T_STEPS 1024
#define NB      64
#define DIN     128
#define HID     256
#define WPG     16

typedef unsigned short u16;
typedef unsigned int   u32;
typedef unsigned long long u64;
typedef __attribute__((ext_vector_type(8))) short short8;
typedef __attribute__((ext_vector_type(4))) float f32x4;

// ws byte offsets
#define WG_OFF   0u          // bf16 weights [2][1024 rows j*4+q][384 k] = 1,572,864 B
#define BIAS_OFF 1572864u    // f32 [2][1024]
#define XB_OFF   1581056u    // bf16 x [1024][64][128] = 16,777,216 B
#define HB_OFF   18358272u   // u16 hbuf [2 par][8 grp][16 b][256 j] = 131,072 B
#define FL_OFF   18489344u   // u32 flags [8 grp][1024 steps] = 32,768 B

#define OUT_MAIN (T_STEPS * NB * 2 * HID)
#define TAIL_H   OUT_MAIN
#define TAIL_C   (OUT_MAIN + 2 * NB * HID)

__device__ __forceinline__ u16 f2bf(float f) {
  unsigned u = __float_as_uint(f);
  return (u16)((u + 0x7fffu + ((u >> 16) & 1u)) >> 16);  // RNE
}
__device__ __forceinline__ float sigm(float v) { return 1.f / (1.f + __expf(-v)); }
__device__ __forceinline__ float tanh_fast(float x) {
  float e = __expf(-2.f * fabsf(x));
  float r = (1.f - e) / (1.f + e);
  return x < 0.f ? -r : r;
}

__global__ void prep_kernel(const float* __restrict__ x,
                            const float* __restrict__ Wih_f, const float* __restrict__ Whh_f,
                            const float* __restrict__ bih_f, const float* __restrict__ bhh_f,
                            const float* __restrict__ Wih_r, const float* __restrict__ Whh_r,
                            const float* __restrict__ bih_r, const float* __restrict__ bhh_r,
                            const float* __restrict__ hx,
                            u16* __restrict__ Wg, float* __restrict__ bias4,
                            u16* __restrict__ xb, u16* __restrict__ hbuf,
                            u32* __restrict__ flags) {
  // segments: W 786432 | bias 2048 | xb 8388608 | hx-cells 32768 | flags 8192
  const int total = 786432 + 2048 + 8388608 + 32768 + 8192;
  for (int i = blockIdx.x * blockDim.x + threadIdx.x; i < total;
       i += gridDim.x * blockDim.x) {
    if (i < 786432) {
      int d = i / 393216;
      int r = i - d * 393216;
      int rowg = r / 384, k = r - rowg * 384;   // rowg = j*4+q interleaved
      int j = rowg >> 2, q = rowg & 3;
      int g = q * HID + j;                      // torch gate row
      const float* Wih = d ? Wih_r : Wih_f;
      const float* Whh = d ? Whh_r : Whh_f;
      float v = (k < DIN) ? Wih[g * DIN + k] : Whh[g * HID + (k - DIN)];
      Wg[i] = f2bf(v);
    } else if (i < 786432 + 2048) {
      int r = i - 786432;
      int d = r >> 10, rowg = r & 1023;
      int j = rowg >> 2, q = rowg & 3;
      int g = q * HID + j;
      bias4[r] = d ? (bih_r[g] + bhh_r[g]) : (bih_f[g] + bhh_f[g]);
    } else if (i < 786432 + 2048 + 8388608) {
      int r = i - (786432 + 2048);
      xb[r] = f2bf(x[r]);                       // [t][b][k]
    } else if (i < 786432 + 2048 + 8388608 + 32768) {
      int r = i - (786432 + 2048 + 8388608);    // (d*64+b)*256 + j
      int d = r >> 14, b = (r >> 8) & 63, j = r & 255;
      int grp = d * 4 + (b >> 4), bb = b & 15;
      hbuf[((size_t)(8 + grp) * 16 + bb) * 256 + j] = f2bf(hx[r]);  // parity 1
      hbuf[((size_t)(0 + grp) * 16 + bb) * 256 + j] = 0;            // parity 0
    } else {
      int r = i - (786432 + 2048 + 8388608 + 32768);  // g*1024 + s
      flags[r] = ((r & 1023) == 0) ? (u32)WPG : 0u;   // step 0 pre-released
    }
  }
}

#define MFMA __builtin_amdgcn_mfma_f32_16x16x32_bf16
#define ALD64(P) __hip_atomic_load((P), __ATOMIC_RELAXED, __HIP_MEMORY_SCOPE_AGENT)

// 128 WGs x 256 thr. grp = bid&7 (co-XCD under round-robin), jsl = bid>>3.
// grp = d*4 + btile: 8 groups x 16 WGs. Per WG: 64 gate rows, 16 batches.
// r17 (2049us champion) with ONE change: wave-autonomous uniform poll on the
// fetch_add counter (broadcast load, scalar branch) and B4 deleted -- each
// wave self-releases and issues its h loads without the tid0->barrier hop.
__global__ __launch_bounds__(256, 1) void lstm_r19(
    const u16* __restrict__ Wg, const float* __restrict__ bias4,
    const u16* __restrict__ xb, const float* __restrict__ cx,
    u16* __restrict__ hbuf, u32* __restrict__ flags,
    float* __restrict__ out) {
  extern __shared__ char smem[];
  u16* xsh  = (u16*)smem;                 // [2][16][136]  8,704 B
  u16* hsh  = (u16*)(smem + 8704);        // [16][264]     8,448 B
  float* gl = (float*)(smem + 17152);     // [16][68]      4,352 B  (tot 21,504)

  const int tid = threadIdx.x;
  const int bid = blockIdx.x;
  const int grp = bid & 7;
  const int jsl = bid >> 3;
  const int d = grp >> 2, b0 = (grp & 3) * 16;
  const int w = tid >> 6, l = tid & 63;

  // one-time: 12 weight fragments -> named VGPRs (r13/r17-proven, no spill)
  const u16* wgb = Wg + ((size_t)(d * 1024 + jsl * 64 + w * 16 + (l & 15))) * 384
                      + (l >> 4) * 8;
  short8 Wx0 = *(const short8*)(wgb + 0);
  short8 Wx1 = *(const short8*)(wgb + 32);
  short8 Wx2 = *(const short8*)(wgb + 64);
  short8 Wx3 = *(const short8*)(wgb + 96);
  short8 Wh0 = *(const short8*)(wgb + 128);
  short8 Wh1 = *(const short8*)(wgb + 160);
  short8 Wh2 = *(const short8*)(wgb + 192);
  short8 Wh3 = *(const short8*)(wgb + 224);
  short8 Wh4 = *(const short8*)(wgb + 256);
  short8 Wh5 = *(const short8*)(wgb + 288);
  short8 Wh6 = *(const short8*)(wgb + 320);
  short8 Wh7 = *(const short8*)(wgb + 352);
  const float bv = bias4[d * 1024 + jsl * 64 + w * 16 + (l & 15)];

  // elementwise identity: 1 cell/thread: eb = batch, ej = local j
  const int eb = tid >> 4, ej = tid & 15;
  const int jglob = jsl * 16 + ej;
  float c_reg = cx[((size_t)d * NB + b0 + eb) * HID + jglob];

  const int xr_row = tid >> 4;            // x stage row (16 batches)
  const int xc = (tid & 15) * 8;          // 8 u16 = 16 B per thread
  const int pb = tid >> 4;                // h consumer batch
  const int cj0 = (tid & 15) * 16;        // 16 h cells per thread

  // prologue: stage x(t0), prefetch x(t1), issue h(init) loads (parity 1)
  { int t0 = d ? 1023 : 0;
    *(uint4*)&xsh[(0 * 16 + xr_row) * 136 + xc] =
        *(const uint4*)&xb[((size_t)t0 * NB + b0 + xr_row) * DIN + xc]; }
  uint4 xv;
  { int t1 = d ? 1022 : 1;
    xv = *(const uint4*)&xb[((size_t)t1 * NB + b0 + xr_row) * DIN + xc]; }
  u64 h0, h1, h2, h3;
  { const u64* hp = (const u64*)(hbuf + ((size_t)(8 + grp) * 16 + pb) * 256 + cj0);
    h0 = ALD64(hp + 0); h1 = ALD64(hp + 1); h2 = ALD64(hp + 2); h3 = ALD64(hp + 3); }
  __syncthreads();

  for (int s = 0; s < T_STEPS; ++s) {
    const int p = s & 1;
    const int t = d ? (1023 - s) : s;

    // park x(s+1) into the other buffer
    if (s < 1023) *(uint4*)&xsh[((p ^ 1) * 16 + xr_row) * 136 + xc] = xv;

    // x-part MFMA (hides in-flight h loads); weights from VGPRs
    f32x4 acc = {bv, bv, bv, bv};
    {
      const u16* xr = &xsh[(p * 16 + (l & 15)) * 136 + (l >> 4) * 8];
      acc = MFMA(*(const short8*)(xr + 0),  Wx0, acc, 0, 0, 0);
      acc = MFMA(*(const short8*)(xr + 32), Wx1, acc, 0, 0, 0);
      acc = MFMA(*(const short8*)(xr + 64), Wx2, acc, 0, 0, 0);
      acc = MFMA(*(const short8*)(xr + 96), Wx3, acc, 0, 0, 0);
    }
    // park h (waits vmcnt on h regs only)
    {
      uint4 H0, H1;
      H0.x = (u32)h0; H0.y = (u32)(h0 >> 32); H0.z = (u32)h1; H0.w = (u32)(h1 >> 32);
      H1.x = (u32)h2; H1.y = (u32)(h2 >> 32); H1.z = (u32)h3; H1.w = (u32)(h3 >> 32);
      *(uint4*)&hsh[pb * 264 + cj0] = H0;
      *(uint4*)&hsh[pb * 264 + cj0 + 8] = H1;
    }
    asm volatile("s_waitcnt lgkmcnt(0)" ::: "memory");
    __builtin_amdgcn_s_barrier();                // B1: h parked

    // h-part MFMA: weights from registers, h fragments from LDS
    {
      const u16* hr = &hsh[(l & 15) * 264 + (l >> 4) * 8];
      acc = MFMA(*(const short8*)(hr + 0),   Wh0, acc, 0, 0, 0);
      acc = MFMA(*(const short8*)(hr + 32),  Wh1, acc, 0, 0, 0);
      acc = MFMA(*(const short8*)(hr + 64),  Wh2, acc, 0, 0, 0);
      acc = MFMA(*(const short8*)(hr + 96),  Wh3, acc, 0, 0, 0);
      acc = MFMA(*(const short8*)(hr + 128), Wh4, acc, 0, 0, 0);
      acc = MFMA(*(const short8*)(hr + 160), Wh5, acc, 0, 0, 0);
      acc = MFMA(*(const short8*)(hr + 192), Wh6, acc, 0, 0, 0);
      acc = MFMA(*(const short8*)(hr + 224), Wh7, acc, 0, 0, 0);
    }
    {
      int n = w * 16 + (l & 15);
      int m0 = (l >> 4) * 4;
      gl[(m0 + 0) * 68 + n] = acc[0]; gl[(m0 + 1) * 68 + n] = acc[1];
      gl[(m0 + 2) * 68 + n] = acc[2]; gl[(m0 + 3) * 68 + n] = acc[3];
    }
    asm volatile("s_waitcnt lgkmcnt(0)" ::: "memory");
    __builtin_amdgcn_s_barrier();                // B2: gates published

    // elementwise (all 256 threads) + agent h-store
    f32x4 g4 = *(const f32x4*)&gl[eb * 68 + 4 * ej];
    float ii = sigm(g4[0]), ff = sigm(g4[1]);
    float gg = tanh_fast(g4[2]), oo = sigm(g4[3]);
    float c = ff * c_reg + ii * gg;
    c_reg = c;
    float h = oo * tanh_fast(c);
    u16 hb16 = f2bf(h);
    __hip_atomic_store(hbuf + ((size_t)(p * 8 + grp) * 16 + eb) * 256 + jglob,
                       hb16, __ATOMIC_RELAXED, __HIP_MEMORY_SCOPE_AGENT);
    asm volatile("s_waitcnt vmcnt(0)" ::: "memory");   // h at LLC
    __builtin_amdgcn_s_barrier();                // B3: all h stores drained
    if (tid == 0 && s < 1023)
      __hip_atomic_fetch_add(flags + grp * 1024 + (s + 1), 1u,
                             __ATOMIC_RELAXED, __HIP_MEMORY_SCOPE_AGENT);
    // fire-and-forget stores after the flag
    out[((size_t)t * NB + b0 + eb) * (2 * HID) + d * HID + jglob] = h;
    if (s == 1023) {
      out[TAIL_H + ((size_t)d * NB + b0 + eb) * HID + jglob] = h;
      out[TAIL_C + ((size_t)d * NB + b0 + eb) * HID + jglob] = c;
    }
    // x prefetch for s+2
    if (s < 1022) {
      int tn = d ? (1021 - s) : (s + 2);
      xv = *(const uint4*)&xb[((size_t)tn * NB + b0 + xr_row) * DIN + xc];
    }
    if (s < 1023) {
      // wave-autonomous uniform poll: all lanes load the SAME counter word
      // (1 broadcast transaction/wave/round, scalar branch, no divergence).
      // Each wave self-releases; no B4, no tid0 fan-out, no sleep quantum.
      const u32* fp = flags + grp * 1024 + (s + 1);
      while (__hip_atomic_load(fp, __ATOMIC_RELAXED, __HIP_MEMORY_SCOPE_AGENT) < WPG) { }
      // issue h(s) loads (parity p) -- hidden under next step's x-GEMM
      const u64* hp = (const u64*)(hbuf + ((size_t)(p * 8 + grp) * 16 + pb) * 256 + cj0);
      h0 = ALD64(hp + 0); h1 = ALD64(hp + 1); h2 = ALD64(hp + 2); h3 = ALD64(hp + 3);
    }
  }
}

extern "C" void kernel_launch(void* const* d_in, const int* in_sizes, int n_in,
                              void* d_out, int out_size, void* d_ws, size_t ws_size,
                              hipStream_t stream) {
  const float* x     = (const float*)d_in[0];
  const float* hx    = (const float*)d_in[1];
  const float* cx    = (const float*)d_in[2];
  const float* Wih_f = (const float*)d_in[3];
  const float* Whh_f = (const float*)d_in[4];
  const float* bih_f = (const float*)d_in[5];
  const float* bhh_f = (const float*)d_in[6];
  const float* Wih_r = (const float*)d_in[7];
  const float* Whh_r = (const float*)d_in[8];
  const float* bih_r = (const float*)d_in[9];
  const float* bhh_r = (const float*)d_in[10];
  float* out = (float*)d_out;

  u16* Wg      = (u16*)((char*)d_ws + WG_OFF);
  float* bias4 = (float*)((char*)d_ws + BIAS_OFF);
  u16* xb      = (u16*)((char*)d_ws + XB_OFF);
  u16* hbuf    = (u16*)((char*)d_ws + HB_OFF);
  u32* flags   = (u32*)((char*)d_ws + FL_OFF);

  // Request 86,016 B dynamic LDS (uses ~21.5 KB): forces 1 WG/CU.
  hipFuncSetAttribute((const void*)lstm_r19,
                      hipFuncAttributeMaxDynamicSharedMemorySize, 86016);

  hipLaunchKernelGGL(prep_kernel, dim3(2048), dim3(256), 0, stream,
                     x, Wih_f, Whh_f, bih_f, bhh_f, Wih_r, Whh_r, bih_r, bhh_r,
                     hx, Wg, bias4, xb, hbuf, flags);
  hipLaunchKernelGGL(lstm_r19, dim3(128), dim3(256), 86016, stream,
                     Wg, bias4, xb, cx, hbuf, flags, out);
}